// Round 4
// baseline (1405.459 us; speedup 1.0000x reference)
//
#include <hip/hip_runtime.h>
#include <hip/hip_bf16.h>
#include <hip/hip_cooperative_groups.h>

namespace cg = cooperative_groups;

// Problem constants
static constexpr int PN = 16384;  // paths
static constexpr int TT = 8;      // seq len
static constexpr int LN = 4096;   // links
static constexpr int KG = 16;     // path_to_link K
static constexpr int NN = 2048;   // nodes
static constexpr int K2G = 32;    // path_to_node K2
static constexpr int MG = 8;      // link_to_node M
static constexpr int ITER = 8;
static constexpr int GRID = 512;  // cooperative grid (2/CU co-residency floor)

typedef __attribute__((ext_vector_type(8))) short short8b;   // 8 bf16 (4 VGPRs)
typedef __attribute__((ext_vector_type(4))) float f32x4;

__device__ __forceinline__ float sigmoidf_(float x) {
    return 1.0f / (1.0f + __expf(-x));
}
__device__ __forceinline__ float tanhf_(float x) {
    float e = __expf(2.0f * x);
    return 1.0f - 2.0f / (e + 1.0f);
}
__device__ __forceinline__ float softplusf_(float x) {
    return fmaxf(x, 0.0f) + log1pf(__expf(-fabsf(x)));
}
__device__ __forceinline__ unsigned short f2bf(float f) {
    unsigned int x = __float_as_uint(f);
    unsigned int r = (x + 0x7fffu + ((x >> 16) & 1u)) >> 16;
    return (unsigned short)r;
}
__device__ __forceinline__ float bf2f(unsigned short u) {
    return __uint_as_float(((unsigned int)u) << 16);
}

struct MegaArgs {
    const float *ft, *fpk, *fps, *cap;
    const float *pe_w1, *pe_b1, *pe_w2, *pe_b2;
    const float *le_w1, *le_b1, *le_w2, *le_b2;
    const float *de_w1, *de_b1, *de_w2, *de_b2;
    const float *pgru_wx, *pgru_wh, *pgru_bx, *pgru_bh;
    const float *lgru_wx, *lgru_wh, *lgru_bx, *lgru_bh;
    const float *dgru_wx, *dgru_wh, *dgru_bx, *dgru_bh;
    const int *ltp, *ntp, *ptl, *ptn, *ltn, *nodes, *ldt;
    unsigned short *pwxT, *pwhT, *lwxT, *lwhT, *dwxT, *dwhT;
    unsigned short *pssb;
    float *link_state, *device_state;
};

// ---------------------------------------------------------------------------
// Edge (link/device) GRU update core. Kg compile-time => unrolled gathers.
// LDS aliased into the pscan Xs scratch region (Hb region untouched).
// ---------------------------------------------------------------------------
template <int Kg>
__device__ __forceinline__ void edge_core(
    char* smem, int tid, int w, int c, int q, int d,
    const int* __restrict__ p2e, int r0,
    const unsigned short* __restrict__ pssb, float* __restrict__ state,
    const short8b (&fx)[3][2], const short8b (&fh)[3][2],
    float bz, float br, float bxc, float bhc)
{
    int* idxs = (int*)smem;                                   // [16*Kg*2] <=4KB
    unsigned short (*Ab)[72]  = (unsigned short(*)[72])(smem + 4096);
    unsigned short (*Hbs)[72] = (unsigned short(*)[72])(smem + 6400);
    float (*Hf)[68]           = (float(*)[68])(smem + 8704);

    for (int i = tid; i < 16 * Kg * 2; i += 256)
        idxs[i] = p2e[(size_t)r0 * Kg * 2 + i];
    __syncthreads();
    {
        int r = tid >> 4, c4 = (tid & 15) * 4;
        int row = r0 + r;
        float4 s = {0.f, 0.f, 0.f, 0.f};
#pragma unroll
        for (int k = 0; k < Kg; ++k) {
            int pi = idxs[(r * Kg + k) * 2];
            int ti = idxs[(r * Kg + k) * 2 + 1];
            ushort4 v = *(const ushort4*)(pssb + ((size_t)pi * TT + ti - 1) * 64 + c4);
            s.x += bf2f(v.x); s.y += bf2f(v.y);
            s.z += bf2f(v.z); s.w += bf2f(v.w);
        }
        ushort4 ua;
        ua.x = f2bf(s.x); ua.y = f2bf(s.y); ua.z = f2bf(s.z); ua.w = f2bf(s.w);
        *(ushort4*)&Ab[r][c4] = ua;
        float4 hv = *(const float4*)(state + (size_t)row * 64 + c4);
        *(float4*)&Hf[r][c4] = hv;
        ushort4 uh;
        uh.x = f2bf(hv.x); uh.y = f2bf(hv.y); uh.z = f2bf(hv.z); uh.w = f2bf(hv.w);
        *(ushort4*)&Hbs[r][c4] = uh;
    }
    __syncthreads();
    f32x4 ax[3], ah[3];
#pragma unroll
    for (int g = 0; g < 3; ++g) {
        ax[g] = (f32x4){0.f, 0.f, 0.f, 0.f};
        ah[g] = (f32x4){0.f, 0.f, 0.f, 0.f};
    }
#pragma unroll
    for (int kt = 0; kt < 2; ++kt) {
        short8b aA = *(const short8b*)&Ab[c][kt * 32 + q * 8];
        short8b aH = *(const short8b*)&Hbs[c][kt * 32 + q * 8];
#pragma unroll
        for (int g = 0; g < 3; ++g) {
            ax[g] = __builtin_amdgcn_mfma_f32_16x16x32_bf16(aA, fx[g][kt], ax[g], 0, 0, 0);
            ah[g] = __builtin_amdgcn_mfma_f32_16x16x32_bf16(aH, fh[g][kt], ah[g], 0, 0, 0);
        }
    }
#pragma unroll
    for (int r = 0; r < 4; ++r) {
        int m = q * 4 + r;
        float z  = sigmoidf_(ax[0][r] + ah[0][r] + bz);
        float rr = sigmoidf_(ax[1][r] + ah[1][r] + br);
        float cc = tanhf_(ax[2][r] + bxc + rr * (ah[2][r] + bhc));
        float hn = z * Hf[m][d] + (1.0f - z) * cc;
        state[(size_t)(r0 + m) * 64 + d] = hn;
    }
}

// ---------------------------------------------------------------------------
// Cooperative mega-kernel: wT + encoders + 8x(pscan + edge) in ONE launch.
// Block b owns paths [32b, 32b+32): their h never leaves the block.
// ---------------------------------------------------------------------------
__global__ __launch_bounds__(256, 2) void k_mega(MegaArgs A)
{
    cg::grid_group grid = cg::this_grid();
    __shared__ __align__(16) char smem[46080];
    // pscan views
    unsigned short (*Xs)[32][72] = (unsigned short(*)[32][72])smem;   // [8][32][72]
    unsigned short (*Hb)[32][72] = (unsigned short(*)[32][72])(smem + 36864); // [2][32][72]
    // encoder views (alias into Xs scratch)
    float* Hf32 = (float*)smem;             // [32][64] fp32 h0
    float* h1s  = (float*)(smem + 8192);    // [4][64]

    int tid = threadIdx.x;
    int bid = blockIdx.x;
    int lane = tid & 63, w = tid >> 6, c = lane & 15, q = lane >> 4;
    int d = 16 * w + c;
    int p0 = bid * 32;

    // ===== Phase E1a: GRU weight transpose+cast fp32[64][192] -> bf16[192][64]
    {
        const float* srcs[6] = {A.pgru_wx, A.pgru_wh, A.lgru_wx,
                                A.lgru_wh, A.dgru_wx, A.dgru_wh};
        unsigned short* dsts[6] = {A.pwxT, A.pwhT, A.lwxT, A.lwhT, A.dwxT, A.dwhT};
        for (int i = bid * 256 + tid; i < 6 * 12288; i += GRID * 256) {
            int mi = i / 12288, o = i - mi * 12288;
            int n = o >> 6, k = o & 63;
            dsts[mi][o] = f2bf(srcs[mi][k * 192 + n]);
        }
    }
    // ===== Phase E1b: path encoder for own 32 paths -> Hf32 (LDS only)
    {
        int rl = tid >> 6, dd = tid & 63;
        for (int rp = 0; rp < 8; ++rp) {
            int rowl = rp * 4 + rl;
            int row = p0 + rowl;
            float x0 = A.ft[row]  * 1e-4f;
            float x1 = A.fpk[row] * 1e-3f;
            float x2 = A.fps[row] * 1e-3f;
            float h = A.pe_b1[dd] + x0 * A.pe_w1[dd] + x1 * A.pe_w1[64 + dd]
                    + x2 * A.pe_w1[128 + dd];
            h1s[rl * 64 + dd] = fmaxf(h, 0.0f);
            __syncthreads();
            float acc = A.pe_b2[dd];
#pragma unroll 8
            for (int k = 0; k < 64; ++k) acc += h1s[rl * 64 + k] * A.pe_w2[k * 64 + dd];
            Hf32[rowl * 64 + dd] = fmaxf(acc, 0.0f);
            __syncthreads();
        }
    }
    // ===== Phase E1c: link encoder for own 8 links -> link_state (global)
    {
        int rl = tid >> 6, dd = tid & 63;
        for (int lp = 0; lp < 2; ++lp) {
            int row = bid * 8 + lp * 4 + rl;
            float v = 0.0f;
            if (dd < 16) v = A.ft[A.ptl[(row * 16 + dd) * 2]];
            v += __shfl_down(v, 8);
            v += __shfl_down(v, 4);
            v += __shfl_down(v, 2);
            v += __shfl_down(v, 1);
            float ssum = __shfl(v, 0);
            float cv = A.cap[row];
            float load = ssum / (cv * 1e9f);
            float x0 = cv * 0.01f;
            float x2 = (A.ldt[row] == 0) ? 1.0f : 0.0f;
            float h = A.le_b1[dd] + x0 * A.le_w1[dd] + load * A.le_w1[64 + dd]
                    + x2 * A.le_w1[128 + dd];
            h1s[rl * 64 + dd] = fmaxf(h, 0.0f);
            __syncthreads();
            float acc = A.le_b2[dd];
#pragma unroll 8
            for (int k = 0; k < 64; ++k) acc += h1s[rl * 64 + k] * A.le_w2[k * 64 + dd];
            A.link_state[(size_t)row * 64 + dd] = fmaxf(acc, 0.0f);
            __syncthreads();
        }
    }
    grid.sync();   // link_state visible everywhere
    // ===== Phase E2: device encoder for own 4 nodes -> device_state (global)
    {
        int rl = tid >> 6, dd = tid & 63;
        int row = bid * 4 + rl;
        float s = 0.0f;
#pragma unroll
        for (int m = 0; m < MG; ++m)
            s += A.link_state[(size_t)A.ltn[row * MG + m] * 64 + dd];
#pragma unroll
        for (int o = 32; o > 0; o >>= 1) s += __shfl_xor(s, o);
        float dlm = s * (1.0f / 64.0f);
        float enc = (A.nodes[row] == 0) ? 1.0f : 0.0f;
        float h = A.de_b1[dd] + enc * A.de_w1[dd] + dlm * A.de_w1[64 + dd];
        h1s[rl * 64 + dd] = fmaxf(h, 0.0f);
        __syncthreads();
        float acc = A.de_b2[dd];
#pragma unroll 8
        for (int k = 0; k < 64; ++k) acc += h1s[rl * 64 + k] * A.de_w2[k * 64 + dd];
        A.device_state[(size_t)row * 64 + dd] = fmaxf(acc, 0.0f);
        __syncthreads();
    }
    // ===== Preload persistent fragments/biases; init hold + Hb[0] from Hf32
    short8b fx[3][2], fh[3][2];
#pragma unroll
    for (int g = 0; g < 3; ++g)
#pragma unroll
        for (int kt = 0; kt < 2; ++kt) {
            int off = (g * 64 + 16 * w + c) * 64 + kt * 32 + q * 8;
            fx[g][kt] = *(const short8b*)(A.pwxT + off);
            fh[g][kt] = *(const short8b*)(A.pwhT + off);
        }
    float bz = A.pgru_bx[d] + A.pgru_bh[d];
    float br = A.pgru_bx[64 + d] + A.pgru_bh[64 + d];
    float bxc = A.pgru_bx[128 + d];
    float bhc = A.pgru_bh[128 + d];
    float hold[2][4];
#pragma unroll
    for (int mt = 0; mt < 2; ++mt)
#pragma unroll
        for (int r_ = 0; r_ < 4; ++r_)
            hold[mt][r_] = Hf32[(mt * 16 + q * 4 + r_) * 64 + d];
    {
        int r = tid >> 3, c0 = (tid & 7) * 8;
        float4 a = *(const float4*)&Hf32[r * 64 + c0];
        float4 b = *(const float4*)&Hf32[r * 64 + c0 + 4];
        ushort4 u0, u1;
        u0.x = f2bf(a.x); u0.y = f2bf(a.y); u0.z = f2bf(a.z); u0.w = f2bf(a.w);
        u1.x = f2bf(b.x); u1.y = f2bf(b.y); u1.z = f2bf(b.z); u1.w = f2bf(b.w);
        *(ushort4*)&Hb[0][r][c0] = u0;
        *(ushort4*)&Hb[0][r][c0 + 4] = u1;
    }
    // edge role setup (blocks 0..255: links, 256..383: devices)
    bool isEdge = bid < (LN / 16 + NN / 16);
    bool isLink = bid < (LN / 16);
    short8b efx[3][2], efh[3][2];
    float ebz = 0.f, ebr = 0.f, ebxc = 0.f, ebhc = 0.f;
    const int* ep2e = A.ptl;
    float* estate = A.link_state;
    int er0 = 0;
    if (isEdge) {
        const unsigned short* ewxT = isLink ? A.lwxT : A.dwxT;
        const unsigned short* ewhT = isLink ? A.lwhT : A.dwhT;
        const float* ebx = isLink ? A.lgru_bx : A.dgru_bx;
        const float* ebh = isLink ? A.lgru_bh : A.dgru_bh;
        ep2e = isLink ? A.ptl : A.ptn;
        estate = isLink ? A.link_state : A.device_state;
        er0 = (isLink ? bid : bid - LN / 16) * 16;
#pragma unroll
        for (int g = 0; g < 3; ++g)
#pragma unroll
            for (int kt = 0; kt < 2; ++kt) {
                int off = (g * 64 + 16 * w + c) * 64 + kt * 32 + q * 8;
                efx[g][kt] = *(const short8b*)(ewxT + off);
                efh[g][kt] = *(const short8b*)(ewhT + off);
            }
        ebz = ebx[d] + ebh[d];
        ebr = ebx[64 + d] + ebh[64 + d];
        ebxc = ebx[128 + d];
        ebhc = ebh[128 + d];
    }
    grid.sync();   // device_state + transposed weights visible

    // ===== 8 message-passing iterations =====
    for (int it = 0; it < ITER; ++it) {
        // ---- pscan: gather x rows (clobbers Xs/Hf32 scratch region)
        {
            int t = tid >> 5, m = tid & 31;
            int gi = (p0 + m) * TT + t;
            int il = A.ltp[gi], in = A.ntp[gi];
            const float4* l4 = (const float4*)(A.link_state + (size_t)il * 64);
            const float4* n4 = (const float4*)(A.device_state + (size_t)in * 64);
#pragma unroll
            for (int j = 0; j < 16; ++j) {
                float4 a = l4[j], b = n4[j];
                ushort4 u;
                u.x = f2bf(a.x + b.x); u.y = f2bf(a.y + b.y);
                u.z = f2bf(a.z + b.z); u.w = f2bf(a.w + b.w);
                *(ushort4*)&Xs[t][m][j * 4] = u;
            }
        }
        __syncthreads();
        // ---- 8 GRU steps
        for (int t = 0; t < TT; ++t) {
            int rb = t & 1, wb = rb ^ 1;
            f32x4 ax[3][2], ah[3][2];
#pragma unroll
            for (int g = 0; g < 3; ++g)
#pragma unroll
                for (int mt = 0; mt < 2; ++mt) {
                    ax[g][mt] = (f32x4){0.f, 0.f, 0.f, 0.f};
                    ah[g][mt] = (f32x4){0.f, 0.f, 0.f, 0.f};
                }
#pragma unroll
            for (int kt = 0; kt < 2; ++kt) {
                short8b aX0 = *(const short8b*)&Xs[t][c][kt * 32 + q * 8];
                short8b aX1 = *(const short8b*)&Xs[t][16 + c][kt * 32 + q * 8];
                short8b aH0 = *(const short8b*)&Hb[rb][c][kt * 32 + q * 8];
                short8b aH1 = *(const short8b*)&Hb[rb][16 + c][kt * 32 + q * 8];
#pragma unroll
                for (int g = 0; g < 3; ++g) {
                    ax[g][0] = __builtin_amdgcn_mfma_f32_16x16x32_bf16(aX0, fx[g][kt], ax[g][0], 0, 0, 0);
                    ax[g][1] = __builtin_amdgcn_mfma_f32_16x16x32_bf16(aX1, fx[g][kt], ax[g][1], 0, 0, 0);
                    ah[g][0] = __builtin_amdgcn_mfma_f32_16x16x32_bf16(aH0, fh[g][kt], ah[g][0], 0, 0, 0);
                    ah[g][1] = __builtin_amdgcn_mfma_f32_16x16x32_bf16(aH1, fh[g][kt], ah[g][1], 0, 0, 0);
                }
            }
#pragma unroll
            for (int mt = 0; mt < 2; ++mt)
#pragma unroll
                for (int r_ = 0; r_ < 4; ++r_) {
                    float z  = sigmoidf_(ax[0][mt][r_] + ah[0][mt][r_] + bz);
                    float rr = sigmoidf_(ax[1][mt][r_] + ah[1][mt][r_] + br);
                    float cc = tanhf_(ax[2][mt][r_] + bxc + rr * (ah[2][mt][r_] + bhc));
                    float hn = z * hold[mt][r_] + (1.0f - z) * cc;
                    hold[mt][r_] = hn;
                    Hb[wb][mt * 16 + q * 4 + r_][d] = f2bf(hn);
                }
            __syncthreads();
            // cooperative bf16 pss store
            {
                int r = tid >> 3, c0 = (tid & 7) * 8;
                ushort4 v0 = *(const ushort4*)&Hb[wb][r][c0];
                ushort4 v1 = *(const ushort4*)&Hb[wb][r][c0 + 4];
                ushort4* dst = (ushort4*)(A.pssb + ((size_t)(p0 + r) * TT + t) * 64 + c0);
                dst[0] = v0; dst[1] = v1;
            }
        }
        grid.sync();   // pssb visible to edge blocks
        // ---- edge updates (Hb region untouched; Xs scratch reused)
        if (isEdge) {
            if (isLink)
                edge_core<KG>(smem, tid, w, c, q, d, ep2e, er0, A.pssb, estate,
                              efx, efh, ebz, ebr, ebxc, ebhc);
            else
                edge_core<K2G>(smem, tid, w, c, q, d, ep2e, er0, A.pssb, estate,
                               efx, efh, ebz, ebr, ebxc, ebhc);
        }
        if (it != ITER - 1) grid.sync();   // states visible to next pscan
    }
}

// ---------------------------------------------------------------------------
// Readout MLP (64->32->16->1) + softplus + delay sum. 32 paths/block.
// ---------------------------------------------------------------------------
__global__ __launch_bounds__(256) void k_readout(
    const unsigned short* __restrict__ pssb,
    const float* __restrict__ w1, const float* __restrict__ b1,
    const float* __restrict__ w2, const float* __restrict__ b2,
    const float* __restrict__ w3, const float* __restrict__ b3,
    const float* __restrict__ cap, const int* __restrict__ ltp,
    float* __restrict__ out)
{
    __shared__ __align__(16) float w1s[64 * 32];
    __shared__ __align__(16) float w2s[32 * 16];
    __shared__ float w3s[16], b1s[32], b2s[16];
    __shared__ __align__(16) float Rf[64][68];
    __shared__ float H1[64][34];
    __shared__ float H2[64][18];
    __shared__ float OCs[256];
    int tid = threadIdx.x;
    size_t g0 = (size_t)blockIdx.x * 256;

    for (int i = tid; i < 2048; i += 256) w1s[i] = w1[i];
    for (int i = tid; i < 512; i += 256) w2s[i] = w2[i];
    if (tid < 16) w3s[tid] = w3[tid];
    if (tid < 32) b1s[tid] = b1[tid];
    if (tid < 16) b2s[tid] = b2[tid];
    float b3v = b3[0];

    for (int ch = 0; ch < 4; ++ch) {
        __syncthreads();
#pragma unroll
        for (int u = 0; u < 2; ++u) {
            int li = tid + u * 256;
            int r = li >> 3, c0 = (li & 7) * 8;
            short8b v = *(const short8b*)(pssb + (g0 + ch * 64 + r) * 64 + c0);
            float4 f0, f1;
            f0.x = bf2f((unsigned short)v[0]); f0.y = bf2f((unsigned short)v[1]);
            f0.z = bf2f((unsigned short)v[2]); f0.w = bf2f((unsigned short)v[3]);
            f1.x = bf2f((unsigned short)v[4]); f1.y = bf2f((unsigned short)v[5]);
            f1.z = bf2f((unsigned short)v[6]); f1.w = bf2f((unsigned short)v[7]);
            *(float4*)&Rf[r][c0] = f0;
            *(float4*)&Rf[r][c0 + 4] = f1;
        }
        __syncthreads();
        {
            int r = tid >> 2, jg = tid & 3;
            float acc[8];
#pragma unroll
            for (int j = 0; j < 8; ++j) acc[j] = 0.f;
#pragma unroll 8
            for (int k = 0; k < 64; ++k) {
                float x = Rf[r][k];
                float4 wa = *(const float4*)&w1s[k * 32 + jg * 8];
                float4 wb = *(const float4*)&w1s[k * 32 + jg * 8 + 4];
                acc[0] += x * wa.x; acc[1] += x * wa.y;
                acc[2] += x * wa.z; acc[3] += x * wa.w;
                acc[4] += x * wb.x; acc[5] += x * wb.y;
                acc[6] += x * wb.z; acc[7] += x * wb.w;
            }
#pragma unroll
            for (int j = 0; j < 8; ++j)
                H1[r][jg * 8 + j] = fmaxf(acc[j] + b1s[jg * 8 + j], 0.0f);
        }
        __syncthreads();
        {
            int r = tid >> 2, jg = tid & 3;
            float acc[4];
#pragma unroll
            for (int j = 0; j < 4; ++j) acc[j] = 0.f;
#pragma unroll 8
            for (int k = 0; k < 32; ++k) {
                float x = H1[r][k];
                float4 wv = *(const float4*)&w2s[k * 16 + jg * 4];
                acc[0] += x * wv.x; acc[1] += x * wv.y;
                acc[2] += x * wv.z; acc[3] += x * wv.w;
            }
#pragma unroll
            for (int j = 0; j < 4; ++j)
                H2[r][jg * 4 + j] = fmaxf(acc[j] + b2s[jg * 4 + j], 0.0f);
        }
        __syncthreads();
        if (tid < 64) {
            int r = tid;
            float acc = b3v;
#pragma unroll
            for (int k = 0; k < 16; ++k) acc += H2[r][k] * w3s[k];
            float occ = softplusf_(acc);
            size_t pr = g0 + ch * 64 + r;
            OCs[ch * 64 + r] = occ / cap[ltp[pr]];
        }
    }
    __syncthreads();
    if (tid < 32) {
        float s = 0.0f;
#pragma unroll
        for (int j = 0; j < 8; ++j) s += OCs[tid * 8 + j];
        out[blockIdx.x * 32 + tid] = s;
    }
}

// ---------------------------------------------------------------------------
extern "C" void kernel_launch(void* const* d_in, const int* in_sizes, int n_in,
                              void* d_out, int out_size, void* d_ws, size_t ws_size,
                              hipStream_t stream) {
    const float* ft   = (const float*)d_in[0];
    const float* fpk  = (const float*)d_in[1];
    const float* fps  = (const float*)d_in[2];
    const float* cap  = (const float*)d_in[3];
    const float* pe_w1 = (const float*)d_in[4];
    const float* pe_b1 = (const float*)d_in[5];
    const float* pe_w2 = (const float*)d_in[6];
    const float* pe_b2 = (const float*)d_in[7];
    const float* le_w1 = (const float*)d_in[8];
    const float* le_b1 = (const float*)d_in[9];
    const float* le_w2 = (const float*)d_in[10];
    const float* le_b2 = (const float*)d_in[11];
    const float* de_w1 = (const float*)d_in[12];
    const float* de_b1 = (const float*)d_in[13];
    const float* de_w2 = (const float*)d_in[14];
    const float* de_b2 = (const float*)d_in[15];
    const float* pgru_wx = (const float*)d_in[16];
    const float* pgru_wh = (const float*)d_in[17];
    const float* pgru_bx = (const float*)d_in[18];
    const float* pgru_bh = (const float*)d_in[19];
    const float* lgru_wx = (const float*)d_in[20];
    const float* lgru_wh = (const float*)d_in[21];
    const float* lgru_bx = (const float*)d_in[22];
    const float* lgru_bh = (const float*)d_in[23];
    const float* dgru_wx = (const float*)d_in[24];
    const float* dgru_wh = (const float*)d_in[25];
    const float* dgru_bx = (const float*)d_in[26];
    const float* dgru_bh = (const float*)d_in[27];
    const float* ro_w1 = (const float*)d_in[28];
    const float* ro_b1 = (const float*)d_in[29];
    const float* ro_w2 = (const float*)d_in[30];
    const float* ro_b2 = (const float*)d_in[31];
    const float* ro_w3 = (const float*)d_in[32];
    const float* ro_b3 = (const float*)d_in[33];
    const int* ltp   = (const int*)d_in[34];
    const int* ntp   = (const int*)d_in[35];
    const int* ptl   = (const int*)d_in[36];
    const int* ptn   = (const int*)d_in[37];
    const int* ltn   = (const int*)d_in[38];
    const int* nodes = (const int*)d_in[39];
    const int* ldt   = (const int*)d_in[40];
    float* out = (float*)d_out;

    char* ws = (char*)d_ws;
    float* link_state = (float*)ws;      ws += (size_t)LN * 64 * 4;
    float* device_state = (float*)ws;    ws += (size_t)NN * 64 * 4;
    unsigned short* pssb = (unsigned short*)ws; ws += (size_t)PN * TT * 64 * 2;
    unsigned short* pwxT = (unsigned short*)ws; ws += 192 * 64 * 2;
    unsigned short* pwhT = (unsigned short*)ws; ws += 192 * 64 * 2;
    unsigned short* lwxT = (unsigned short*)ws; ws += 192 * 64 * 2;
    unsigned short* lwhT = (unsigned short*)ws; ws += 192 * 64 * 2;
    unsigned short* dwxT = (unsigned short*)ws; ws += 192 * 64 * 2;
    unsigned short* dwhT = (unsigned short*)ws; ws += 192 * 64 * 2;

    MegaArgs A;
    A.ft = ft; A.fpk = fpk; A.fps = fps; A.cap = cap;
    A.pe_w1 = pe_w1; A.pe_b1 = pe_b1; A.pe_w2 = pe_w2; A.pe_b2 = pe_b2;
    A.le_w1 = le_w1; A.le_b1 = le_b1; A.le_w2 = le_w2; A.le_b2 = le_b2;
    A.de_w1 = de_w1; A.de_b1 = de_b1; A.de_w2 = de_w2; A.de_b2 = de_b2;
    A.pgru_wx = pgru_wx; A.pgru_wh = pgru_wh; A.pgru_bx = pgru_bx; A.pgru_bh = pgru_bh;
    A.lgru_wx = lgru_wx; A.lgru_wh = lgru_wh; A.lgru_bx = lgru_bx; A.lgru_bh = lgru_bh;
    A.dgru_wx = dgru_wx; A.dgru_wh = dgru_wh; A.dgru_bx = dgru_bx; A.dgru_bh = dgru_bh;
    A.ltp = ltp; A.ntp = ntp; A.ptl = ptl; A.ptn = ptn; A.ltn = ltn;
    A.nodes = nodes; A.ldt = ldt;
    A.pwxT = pwxT; A.pwhT = pwhT; A.lwxT = lwxT; A.lwhT = lwhT;
    A.dwxT = dwxT; A.dwhT = dwhT;
    A.pssb = pssb; A.link_state = link_state; A.device_state = device_state;

    void* kargs[] = {(void*)&A};
    hipLaunchCooperativeKernel((void*)k_mega, dim3(GRID), dim3(256), kargs, 0, stream);

    k_readout<<<PN / 32, 256, 0, stream>>>(pssb, ro_w1, ro_b1, ro_w2, ro_b2,
                                           ro_w3, ro_b3, cap, ltp, out);
}

// Round 5
// 448.336 us; speedup vs baseline: 3.1348x; 3.1348x over previous
//
#include <hip/hip_runtime.h>
#include <hip/hip_bf16.h>

// Problem constants
static constexpr int PN = 16384;  // paths
static constexpr int TT = 8;      // seq len
static constexpr int LN = 4096;   // links
static constexpr int KG = 16;     // path_to_link K
static constexpr int NN = 2048;   // nodes
static constexpr int K2G = 32;    // path_to_node K2
static constexpr int MG = 8;      // link_to_node M
static constexpr int ITER = 8;

typedef __attribute__((ext_vector_type(8))) short short8b;   // 8 bf16 (4 VGPRs)
typedef __attribute__((ext_vector_type(4))) float f32x4;

__device__ __forceinline__ float frcp(float x) {
    return __builtin_amdgcn_rcpf(x);   // v_rcp_f32, ~1ulp
}
__device__ __forceinline__ float sigmoidf_(float x) {
    return frcp(1.0f + __expf(-x));
}
__device__ __forceinline__ float tanhf_(float x) {
    // tanh(x) = 1 - 2/(exp(2x)+1)
    return 1.0f - 2.0f * frcp(__expf(2.0f * x) + 1.0f);
}
__device__ __forceinline__ float softplusf_(float x) {
    return fmaxf(x, 0.0f) + log1pf(__expf(-fabsf(x)));
}
__device__ __forceinline__ unsigned short f2bf(float f) {
    unsigned int x = __float_as_uint(f);
    unsigned int r = (x + 0x7fffu + ((x >> 16) & 1u)) >> 16;
    return (unsigned short)r;
}
__device__ __forceinline__ float bf2f(unsigned short u) {
    return __uint_as_float(((unsigned int)u) << 16);
}

// ---------------------------------------------------------------------------
// K_setup: heterogeneous launch.
//   blocks [0,1024)        : path encoder, 16 rows/block, w2 in LDS
//   blocks [1024,1280)     : link encoder, 16 rows/block, w2 in LDS
//   blocks [1280,1568)     : 6x GRU weight transpose fp32[64][192]->bf16[192][64]
// ---------------------------------------------------------------------------
__global__ __launch_bounds__(256) void k_setup(
    const float* __restrict__ ft, const float* __restrict__ fpk,
    const float* __restrict__ fps, const float* __restrict__ cap,
    const int* __restrict__ ptl, const int* __restrict__ ldt,
    const float* __restrict__ pe_w1, const float* __restrict__ pe_b1,
    const float* __restrict__ pe_w2, const float* __restrict__ pe_b2,
    const float* __restrict__ le_w1, const float* __restrict__ le_b1,
    const float* __restrict__ le_w2, const float* __restrict__ le_b2,
    const float* __restrict__ pgru_wx, const float* __restrict__ pgru_wh,
    const float* __restrict__ lgru_wx, const float* __restrict__ lgru_wh,
    const float* __restrict__ dgru_wx, const float* __restrict__ dgru_wh,
    unsigned short* __restrict__ pwxT, unsigned short* __restrict__ pwhT,
    unsigned short* __restrict__ lwxT, unsigned short* __restrict__ lwhT,
    unsigned short* __restrict__ dwxT, unsigned short* __restrict__ dwhT,
    float* __restrict__ path_state, float* __restrict__ link_state)
{
    int b = blockIdx.x;
    int tid = threadIdx.x;
    if (b >= 1280) {
        // ---- weight transpose role ----
        const float* srcs[6] = {pgru_wx, pgru_wh, lgru_wx, lgru_wh, dgru_wx, dgru_wh};
        unsigned short* dsts[6] = {pwxT, pwhT, lwxT, lwhT, dwxT, dwhT};
        int i = (b - 1280) * 256 + tid;     // 0 .. 6*12288-1
        int mi = i / 12288, o = i - mi * 12288;
        int n = o >> 6, k = o & 63;
        dsts[mi][o] = f2bf(srcs[mi][k * 192 + n]);
        return;
    }
    __shared__ __align__(16) float w2s[4096];
    __shared__ float w1s[192], b1s[64], b2s[64];
    __shared__ float h1s[4][64];
    bool isPath = (b < 1024);
    const float* w1p = isPath ? pe_w1 : le_w1;
    const float* b1p = isPath ? pe_b1 : le_b1;
    const float* w2p = isPath ? pe_w2 : le_w2;
    const float* b2p = isPath ? pe_b2 : le_b2;
    for (int i = tid; i < 4096; i += 256) w2s[i] = w2p[i];
    if (tid < 192) w1s[tid] = w1p[tid];
    if (tid < 64) { b1s[tid] = b1p[tid]; b2s[tid] = b2p[tid]; }
    __syncthreads();
    int rl = tid >> 6, d = tid & 63;
    int base = (isPath ? b : (b - 1024)) * 16;
    for (int rp = 0; rp < 4; ++rp) {
        int row = base + rp * 4 + rl;
        float h;
        if (isPath) {
            float x0 = ft[row]  * 1e-4f;
            float x1 = fpk[row] * 1e-3f;
            float x2 = fps[row] * 1e-3f;
            h = b1s[d] + x0 * w1s[d] + x1 * w1s[64 + d] + x2 * w1s[128 + d];
        } else {
            float v = 0.0f;
            if (d < 16) v = ft[ptl[(row * 16 + d) * 2]];
            v += __shfl_down(v, 8);
            v += __shfl_down(v, 4);
            v += __shfl_down(v, 2);
            v += __shfl_down(v, 1);
            float ssum = __shfl(v, 0);
            float cv = cap[row];
            float load = ssum * frcp(cv * 1e9f);
            float x2 = (ldt[row] == 0) ? 1.0f : 0.0f;
            h = b1s[d] + cv * 0.01f * w1s[d] + load * w1s[64 + d] + x2 * w1s[128 + d];
        }
        h1s[rl][d] = fmaxf(h, 0.0f);
        __syncthreads();
        float acc = b2s[d];
#pragma unroll 8
        for (int k = 0; k < 64; ++k) acc += h1s[rl][k] * w2s[k * 64 + d];
        float* dst = isPath ? path_state : link_state;
        dst[(size_t)row * 64 + d] = fmaxf(acc, 0.0f);
        __syncthreads();
    }
}

// ---------------------------------------------------------------------------
// K3: device encoder, w2 staged in LDS
// ---------------------------------------------------------------------------
__global__ __launch_bounds__(256) void k_device_encode(
    const float* __restrict__ link_state, const int* __restrict__ ltn,
    const int* __restrict__ nodes,
    const float* __restrict__ w1, const float* __restrict__ b1,
    const float* __restrict__ w2, const float* __restrict__ b2,
    float* __restrict__ device_state)
{
    __shared__ __align__(16) float w2s[4096];
    __shared__ float h1s[4][64];
    int tid = threadIdx.x;
    for (int i = tid; i < 4096; i += 256) w2s[i] = w2[i];
    int rl = tid >> 6, d = tid & 63;
    int row = blockIdx.x * 4 + rl;
    float s = 0.0f;
#pragma unroll
    for (int m = 0; m < MG; ++m)
        s += link_state[(size_t)ltn[row * MG + m] * 64 + d];
#pragma unroll
    for (int o = 32; o > 0; o >>= 1) s += __shfl_xor(s, o);
    float dlm = s * (1.0f / 64.0f);
    float enc = (nodes[row] == 0) ? 1.0f : 0.0f;
    float h = b1[d] + enc * w1[d] + dlm * w1[64 + d];
    h1s[rl][d] = fmaxf(h, 0.0f);
    __syncthreads();
    float acc = b2[d];
#pragma unroll 8
    for (int k = 0; k < 64; ++k) acc += h1s[rl][k] * w2s[k * 64 + d];
    device_state[(size_t)row * 64 + d] = fmaxf(acc, 0.0f);
}

// ---------------------------------------------------------------------------
// K4: fused x-gather + xproj + 8-step GRU scan, bf16 MFMA 16x16x32.
// 16 paths/block (grid 1024 = 4/CU), hold-state in registers, dbuf bf16 H,
// ONE barrier per step, pss stored bf16 directly from registers.
// ---------------------------------------------------------------------------
__global__ __launch_bounds__(256, 4) void k_pscan(
    const float* __restrict__ ls, const float* __restrict__ dst,
    const int* __restrict__ ltp, const int* __restrict__ ntp,
    const unsigned short* __restrict__ wxT,   // bf16 [192][64]
    const unsigned short* __restrict__ whT,   // bf16 [192][64]
    const float* __restrict__ bx, const float* __restrict__ bh,
    float* __restrict__ path_state, unsigned short* __restrict__ pssb)
{
    __shared__ __align__(16) unsigned short Xs[8][16][72];  // bf16 x, padded
    __shared__ __align__(16) unsigned short Hb[2][16][72];  // bf16 h dbuf
    int tid = threadIdx.x;
    int p0 = blockIdx.x * 16;

    // stage h0 bf16
    {
        int r = tid >> 4, c0 = (tid & 15) * 4;
        float4 a = *(const float4*)(path_state + (size_t)(p0 + r) * 64 + c0);
        ushort4 u;
        u.x = f2bf(a.x); u.y = f2bf(a.y); u.z = f2bf(a.z); u.w = f2bf(a.w);
        *(ushort4*)&Hb[0][r][c0] = u;
    }
    // gather x = ls[ltp] + dst[ntp] -> bf16 Xs[t][m][k]; 2 threads per (m,t)
    {
        int t = tid >> 5, m = (tid >> 1) & 15, half = tid & 1;
        int gi = (p0 + m) * TT + t;
        int il = ltp[gi], in = ntp[gi];
        const float4* l4 = (const float4*)(ls + (size_t)il * 64 + half * 32);
        const float4* n4 = (const float4*)(dst + (size_t)in * 64 + half * 32);
#pragma unroll
        for (int j = 0; j < 8; ++j) {
            float4 a = l4[j], b = n4[j];
            ushort4 u;
            u.x = f2bf(a.x + b.x); u.y = f2bf(a.y + b.y);
            u.z = f2bf(a.z + b.z); u.w = f2bf(a.w + b.w);
            *(ushort4*)&Xs[t][m][half * 32 + j * 4] = u;
        }
    }

    int lane = tid & 63, w = tid >> 6;
    int c = lane & 15, q = lane >> 4;
    int d = 16 * w + c;
    // B-fragments in registers (constant across steps)
    short8b fx[3][2], fh[3][2];
#pragma unroll
    for (int g = 0; g < 3; ++g)
#pragma unroll
        for (int kt = 0; kt < 2; ++kt) {
            int off = (g * 64 + 16 * w + c) * 64 + kt * 32 + q * 8;
            fx[g][kt] = *(const short8b*)(wxT + off);
            fh[g][kt] = *(const short8b*)(whT + off);
        }
    float bz = bx[d] + bh[d];
    float br = bx[64 + d] + bh[64 + d];
    float bxc = bx[128 + d];
    float bhc = bh[128 + d];
    // hold-state (fp32) in registers: lane owns rows q*4+r_, col d
    float hold[4];
#pragma unroll
    for (int r_ = 0; r_ < 4; ++r_)
        hold[r_] = path_state[(size_t)(p0 + q * 4 + r_) * 64 + d];
    __syncthreads();

    for (int t = 0; t < TT; ++t) {
        int rb = t & 1, wb = rb ^ 1;
        f32x4 ax[3], ah[3];
#pragma unroll
        for (int g = 0; g < 3; ++g) {
            ax[g] = (f32x4){0.f, 0.f, 0.f, 0.f};
            ah[g] = (f32x4){0.f, 0.f, 0.f, 0.f};
        }
#pragma unroll
        for (int kt = 0; kt < 2; ++kt) {
            short8b aX = *(const short8b*)&Xs[t][c][kt * 32 + q * 8];
            short8b aH = *(const short8b*)&Hb[rb][c][kt * 32 + q * 8];
#pragma unroll
            for (int g = 0; g < 3; ++g) {
                ax[g] = __builtin_amdgcn_mfma_f32_16x16x32_bf16(aX, fx[g][kt], ax[g], 0, 0, 0);
                ah[g] = __builtin_amdgcn_mfma_f32_16x16x32_bf16(aH, fh[g][kt], ah[g], 0, 0, 0);
            }
        }
#pragma unroll
        for (int r_ = 0; r_ < 4; ++r_) {
            float z  = sigmoidf_(ax[0][r_] + ah[0][r_] + bz);
            float rr = sigmoidf_(ax[1][r_] + ah[1][r_] + br);
            float cc = tanhf_(ax[2][r_] + bxc + rr * (ah[2][r_] + bhc));
            float hn = z * hold[r_] + (1.0f - z) * cc;
            hold[r_] = hn;
            unsigned short u = f2bf(hn);
            Hb[wb][q * 4 + r_][d] = u;
            // direct bf16 pss store from register
            pssb[((size_t)(p0 + q * 4 + r_) * TT + t) * 64 + d] = u;
        }
        __syncthreads();
    }
    // final h (fp32, from registers) -> path_state
#pragma unroll
    for (int r_ = 0; r_ < 4; ++r_)
        path_state[(size_t)(p0 + q * 4 + r_) * 64 + d] = hold[r_];
}

// ---------------------------------------------------------------------------
// K6: merged link+device GRU update. Template Kg => fully unrolled gathers.
// 16 rows/block; indices staged in LDS; pss read as bf16.
// ---------------------------------------------------------------------------
template <int Kg>
__device__ __forceinline__ void edge_body(
    const unsigned short* __restrict__ wxT, const unsigned short* __restrict__ whT,
    const float* __restrict__ bx, const float* __restrict__ bh,
    const int* __restrict__ p2e, const unsigned short* __restrict__ pssb,
    float* __restrict__ state, int blk)
{
    __shared__ int idxs[16 * Kg * 2];
    __shared__ __align__(16) unsigned short Ab[16][72];
    __shared__ __align__(16) unsigned short Hbs[16][72];
    __shared__ __align__(16) float Hf[16][68];
    int tid = threadIdx.x;
    int r0 = blk * 16;
    for (int i = tid; i < 16 * Kg * 2; i += 256)
        idxs[i] = p2e[(size_t)r0 * Kg * 2 + i];
    __syncthreads();
    {
        int r = tid >> 4, c4 = (tid & 15) * 4;
        int row = r0 + r;
        float4 s = {0.f, 0.f, 0.f, 0.f};
#pragma unroll
        for (int k = 0; k < Kg; ++k) {
            int pi = idxs[(r * Kg + k) * 2];
            int ti = idxs[(r * Kg + k) * 2 + 1];
            ushort4 v = *(const ushort4*)(pssb + ((size_t)pi * TT + ti - 1) * 64 + c4);
            s.x += bf2f(v.x); s.y += bf2f(v.y);
            s.z += bf2f(v.z); s.w += bf2f(v.w);
        }
        ushort4 ua;
        ua.x = f2bf(s.x); ua.y = f2bf(s.y); ua.z = f2bf(s.z); ua.w = f2bf(s.w);
        *(ushort4*)&Ab[r][c4] = ua;
        float4 hv = *(const float4*)(state + (size_t)row * 64 + c4);
        *(float4*)&Hf[r][c4] = hv;
        ushort4 uh;
        uh.x = f2bf(hv.x); uh.y = f2bf(hv.y); uh.z = f2bf(hv.z); uh.w = f2bf(hv.w);
        *(ushort4*)&Hbs[r][c4] = uh;
    }
    __syncthreads();
    int lane = tid & 63, w = tid >> 6;
    int c = lane & 15, q = lane >> 4;
    int d = 16 * w + c;
    short8b fx[3][2], fh[3][2];
#pragma unroll
    for (int g = 0; g < 3; ++g)
#pragma unroll
        for (int kt = 0; kt < 2; ++kt) {
            int off = (g * 64 + 16 * w + c) * 64 + kt * 32 + q * 8;
            fx[g][kt] = *(const short8b*)(wxT + off);
            fh[g][kt] = *(const short8b*)(whT + off);
        }
    f32x4 ax[3], ah[3];
#pragma unroll
    for (int g = 0; g < 3; ++g) {
        ax[g] = (f32x4){0.f, 0.f, 0.f, 0.f};
        ah[g] = (f32x4){0.f, 0.f, 0.f, 0.f};
    }
#pragma unroll
    for (int kt = 0; kt < 2; ++kt) {
        short8b aA = *(const short8b*)&Ab[c][kt * 32 + q * 8];
        short8b aH = *(const short8b*)&Hbs[c][kt * 32 + q * 8];
#pragma unroll
        for (int g = 0; g < 3; ++g) {
            ax[g] = __builtin_amdgcn_mfma_f32_16x16x32_bf16(aA, fx[g][kt], ax[g], 0, 0, 0);
            ah[g] = __builtin_amdgcn_mfma_f32_16x16x32_bf16(aH, fh[g][kt], ah[g], 0, 0, 0);
        }
    }
    float bz = bx[d] + bh[d];
    float br = bx[64 + d] + bh[64 + d];
    float bxc = bx[128 + d];
    float bhc = bh[128 + d];
#pragma unroll
    for (int r = 0; r < 4; ++r) {
        int m = q * 4 + r;
        float z  = sigmoidf_(ax[0][r] + ah[0][r] + bz);
        float rr = sigmoidf_(ax[1][r] + ah[1][r] + br);
        float cc = tanhf_(ax[2][r] + bxc + rr * (ah[2][r] + bhc));
        float hn = z * Hf[m][d] + (1.0f - z) * cc;
        state[(size_t)(r0 + m) * 64 + d] = hn;
    }
}

__global__ __launch_bounds__(256) void k_edge_merged(
    const unsigned short* __restrict__ lwxT, const unsigned short* __restrict__ lwhT,
    const float* __restrict__ lbx, const float* __restrict__ lbh,
    const int* __restrict__ ptl,
    const unsigned short* __restrict__ dwxT, const unsigned short* __restrict__ dwhT,
    const float* __restrict__ dbx, const float* __restrict__ dbh,
    const int* __restrict__ ptn,
    const unsigned short* __restrict__ pssb,
    float* __restrict__ link_state, float* __restrict__ device_state)
{
    int b = blockIdx.x;
    if (b < LN / 16) {
        edge_body<KG>(lwxT, lwhT, lbx, lbh, ptl, pssb, link_state, b);
    } else {
        edge_body<K2G>(dwxT, dwhT, dbx, dbh, ptn, pssb, device_state, b - LN / 16);
    }
}

// ---------------------------------------------------------------------------
// K8: readout MLP (64->32->16->1) + softplus + delay sum. 32 paths/block.
// ---------------------------------------------------------------------------
__global__ __launch_bounds__(256) void k_readout(
    const unsigned short* __restrict__ pssb,
    const float* __restrict__ w1, const float* __restrict__ b1,
    const float* __restrict__ w2, const float* __restrict__ b2,
    const float* __restrict__ w3, const float* __restrict__ b3,
    const float* __restrict__ cap, const int* __restrict__ ltp,
    float* __restrict__ out)
{
    __shared__ __align__(16) float w1s[64 * 32];
    __shared__ __align__(16) float w2s[32 * 16];
    __shared__ float w3s[16], b1s[32], b2s[16];
    __shared__ __align__(16) float Rf[64][68];
    __shared__ float H1[64][34];
    __shared__ float H2[64][18];
    __shared__ float OCs[256];
    int tid = threadIdx.x;
    size_t g0 = (size_t)blockIdx.x * 256;

    for (int i = tid; i < 2048; i += 256) w1s[i] = w1[i];
    for (int i = tid; i < 512; i += 256) w2s[i] = w2[i];
    if (tid < 16) w3s[tid] = w3[tid];
    if (tid < 32) b1s[tid] = b1[tid];
    if (tid < 16) b2s[tid] = b2[tid];
    float b3v = b3[0];

    for (int ch = 0; ch < 4; ++ch) {
        __syncthreads();
#pragma unroll
        for (int u = 0; u < 2; ++u) {
            int li = tid + u * 256;
            int r = li >> 3, c0 = (li & 7) * 8;
            short8b v = *(const short8b*)(pssb + (g0 + ch * 64 + r) * 64 + c0);
            float4 f0, f1;
            f0.x = bf2f((unsigned short)v[0]); f0.y = bf2f((unsigned short)v[1]);
            f0.z = bf2f((unsigned short)v[2]); f0.w = bf2f((unsigned short)v[3]);
            f1.x = bf2f((unsigned short)v[4]); f1.y = bf2f((unsigned short)v[5]);
            f1.z = bf2f((unsigned short)v[6]); f1.w = bf2f((unsigned short)v[7]);
            *(float4*)&Rf[r][c0] = f0;
            *(float4*)&Rf[r][c0 + 4] = f1;
        }
        __syncthreads();
        {
            int r = tid >> 2, jg = tid & 3;
            float acc[8];
#pragma unroll
            for (int j = 0; j < 8; ++j) acc[j] = 0.f;
#pragma unroll 8
            for (int k = 0; k < 64; ++k) {
                float x = Rf[r][k];
                float4 wa = *(const float4*)&w1s[k * 32 + jg * 8];
                float4 wb = *(const float4*)&w1s[k * 32 + jg * 8 + 4];
                acc[0] += x * wa.x; acc[1] += x * wa.y;
                acc[2] += x * wa.z; acc[3] += x * wa.w;
                acc[4] += x * wb.x; acc[5] += x * wb.y;
                acc[6] += x * wb.z; acc[7] += x * wb.w;
            }
#pragma unroll
            for (int j = 0; j < 8; ++j)
                H1[r][jg * 8 + j] = fmaxf(acc[j] + b1s[jg * 8 + j], 0.0f);
        }
        __syncthreads();
        {
            int r = tid >> 2, jg = tid & 3;
            float acc[4];
#pragma unroll
            for (int j = 0; j < 4; ++j) acc[j] = 0.f;
#pragma unroll 8
            for (int k = 0; k < 32; ++k) {
                float x = H1[r][k];
                float4 wv = *(const float4*)&w2s[k * 16 + jg * 4];
                acc[0] += x * wv.x; acc[1] += x * wv.y;
                acc[2] += x * wv.z; acc[3] += x * wv.w;
            }
#pragma unroll
            for (int j = 0; j < 4; ++j)
                H2[r][jg * 4 + j] = fmaxf(acc[j] + b2s[jg * 4 + j], 0.0f);
        }
        __syncthreads();
        if (tid < 64) {
            int r = tid;
            float acc = b3v;
#pragma unroll
            for (int k = 0; k < 16; ++k) acc += H2[r][k] * w3s[k];
            float occ = softplusf_(acc);
            size_t pr = g0 + ch * 64 + r;
            OCs[ch * 64 + r] = occ * frcp(cap[ltp[pr]]);
        }
    }
    __syncthreads();
    if (tid < 32) {
        float s = 0.0f;
#pragma unroll
        for (int j = 0; j < 8; ++j) s += OCs[tid * 8 + j];
        out[blockIdx.x * 32 + tid] = s;
    }
}

// ---------------------------------------------------------------------------
extern "C" void kernel_launch(void* const* d_in, const int* in_sizes, int n_in,
                              void* d_out, int out_size, void* d_ws, size_t ws_size,
                              hipStream_t stream) {
    const float* ft   = (const float*)d_in[0];
    const float* fpk  = (const float*)d_in[1];
    const float* fps  = (const float*)d_in[2];
    const float* cap  = (const float*)d_in[3];
    const float* pe_w1 = (const float*)d_in[4];
    const float* pe_b1 = (const float*)d_in[5];
    const float* pe_w2 = (const float*)d_in[6];
    const float* pe_b2 = (const float*)d_in[7];
    const float* le_w1 = (const float*)d_in[8];
    const float* le_b1 = (const float*)d_in[9];
    const float* le_w2 = (const float*)d_in[10];
    const float* le_b2 = (const float*)d_in[11];
    const float* de_w1 = (const float*)d_in[12];
    const float* de_b1 = (const float*)d_in[13];
    const float* de_w2 = (const float*)d_in[14];
    const float* de_b2 = (const float*)d_in[15];
    const float* pgru_wx = (const float*)d_in[16];
    const float* pgru_wh = (const float*)d_in[17];
    const float* pgru_bx = (const float*)d_in[18];
    const float* pgru_bh = (const float*)d_in[19];
    const float* lgru_wx = (const float*)d_in[20];
    const float* lgru_wh = (const float*)d_in[21];
    const float* lgru_bx = (const float*)d_in[22];
    const float* lgru_bh = (const float*)d_in[23];
    const float* dgru_wx = (const float*)d_in[24];
    const float* dgru_wh = (const float*)d_in[25];
    const float* dgru_bx = (const float*)d_in[26];
    const float* dgru_bh = (const float*)d_in[27];
    const float* ro_w1 = (const float*)d_in[28];
    const float* ro_b1 = (const float*)d_in[29];
    const float* ro_w2 = (const float*)d_in[30];
    const float* ro_b2 = (const float*)d_in[31];
    const float* ro_w3 = (const float*)d_in[32];
    const float* ro_b3 = (const float*)d_in[33];
    const int* ltp   = (const int*)d_in[34];
    const int* ntp   = (const int*)d_in[35];
    const int* ptl   = (const int*)d_in[36];
    const int* ptn   = (const int*)d_in[37];
    const int* ltn   = (const int*)d_in[38];
    const int* nodes = (const int*)d_in[39];
    const int* ldt   = (const int*)d_in[40];
    float* out = (float*)d_out;

    char* ws = (char*)d_ws;
    float* path_state = (float*)ws;      ws += (size_t)PN * 64 * 4;
    float* link_state = (float*)ws;      ws += (size_t)LN * 64 * 4;
    float* device_state = (float*)ws;    ws += (size_t)NN * 64 * 4;
    unsigned short* pssb = (unsigned short*)ws; ws += (size_t)PN * TT * 64 * 2;
    unsigned short* pwxT = (unsigned short*)ws; ws += 192 * 64 * 2;
    unsigned short* pwhT = (unsigned short*)ws; ws += 192 * 64 * 2;
    unsigned short* lwxT = (unsigned short*)ws; ws += 192 * 64 * 2;
    unsigned short* lwhT = (unsigned short*)ws; ws += 192 * 64 * 2;
    unsigned short* dwxT = (unsigned short*)ws; ws += 192 * 64 * 2;
    unsigned short* dwhT = (unsigned short*)ws; ws += 192 * 64 * 2;

    k_setup<<<1568, 256, 0, stream>>>(ft, fpk, fps, cap, ptl, ldt,
                                      pe_w1, pe_b1, pe_w2, pe_b2,
                                      le_w1, le_b1, le_w2, le_b2,
                                      pgru_wx, pgru_wh, lgru_wx, lgru_wh,
                                      dgru_wx, dgru_wh,
                                      pwxT, pwhT, lwxT, lwhT, dwxT, dwhT,
                                      path_state, link_state);
    k_device_encode<<<NN / 4, 256, 0, stream>>>(link_state, ltn, nodes, de_w1,
                                                de_b1, de_w2, de_b2, device_state);
    for (int it = 0; it < ITER; ++it) {
        k_pscan<<<PN / 16, 256, 0, stream>>>(link_state, device_state, ltp, ntp,
                                             pwxT, pwhT, pgru_bx, pgru_bh,
                                             path_state, pssb);
        k_edge_merged<<<LN / 16 + NN / 16, 256, 0, stream>>>(
            lwxT, lwhT, lgru_bx, lgru_bh, ptl,
            dwxT, dwhT, dgru_bx, dgru_bh, ptn,
            pssb, link_state, device_state);
    }
    k_readout<<<PN / 32, 256, 0, stream>>>(pssb, ro_w1, ro_b1, ro_w2, ro_b2,
                                           ro_w3, ro_b3, cap, ltp, out);
}

// Round 6
// 444.054 us; speedup vs baseline: 3.1651x; 1.0096x over previous
//
#include <hip/hip_runtime.h>
#include <hip/hip_bf16.h>

// Problem constants
static constexpr int PN = 16384;  // paths
static constexpr int TT = 8;      // seq len
static constexpr int LN = 4096;   // links
static constexpr int KG = 16;     // path_to_link K
static constexpr int NN = 2048;   // nodes
static constexpr int K2G = 32;    // path_to_node K2
static constexpr int MG = 8;      // link_to_node M
static constexpr int ITER = 8;

typedef __attribute__((ext_vector_type(8))) short short8b;   // 8 bf16 (4 VGPRs)
typedef __attribute__((ext_vector_type(4))) float f32x4;

__device__ __forceinline__ float frcp(float x) {
    return __builtin_amdgcn_rcpf(x);   // v_rcp_f32, ~1ulp
}
__device__ __forceinline__ float sigmoidf_(float x) {
    return frcp(1.0f + __expf(-x));
}
__device__ __forceinline__ float tanhf_(float x) {
    return 1.0f - 2.0f * frcp(__expf(2.0f * x) + 1.0f);
}
__device__ __forceinline__ float softplusf_(float x) {
    return fmaxf(x, 0.0f) + log1pf(__expf(-fabsf(x)));
}
__device__ __forceinline__ unsigned short f2bf(float f) {
    unsigned int x = __float_as_uint(f);
    unsigned int r = (x + 0x7fffu + ((x >> 16) & 1u)) >> 16;
    return (unsigned short)r;
}
__device__ __forceinline__ float bf2f(unsigned short u) {
    return __uint_as_float(((unsigned int)u) << 16);
}

// ---------------------------------------------------------------------------
// K_setup: heterogeneous launch.
//   blocks [0,1024)    : path encoder, 16 rows/block, w2 in LDS
//   blocks [1024,1280) : link encoder, 16 rows/block, w2 in LDS
//   blocks [1280,1568) : 6x GRU weight transpose fp32[64][192]->bf16[192][64]
// ---------------------------------------------------------------------------
__global__ __launch_bounds__(256) void k_setup(
    const float* __restrict__ ft, const float* __restrict__ fpk,
    const float* __restrict__ fps, const float* __restrict__ cap,
    const int* __restrict__ ptl, const int* __restrict__ ldt,
    const float* __restrict__ pe_w1, const float* __restrict__ pe_b1,
    const float* __restrict__ pe_w2, const float* __restrict__ pe_b2,
    const float* __restrict__ le_w1, const float* __restrict__ le_b1,
    const float* __restrict__ le_w2, const float* __restrict__ le_b2,
    const float* __restrict__ pgru_wx, const float* __restrict__ pgru_wh,
    const float* __restrict__ lgru_wx, const float* __restrict__ lgru_wh,
    const float* __restrict__ dgru_wx, const float* __restrict__ dgru_wh,
    unsigned short* __restrict__ pwxT, unsigned short* __restrict__ pwhT,
    unsigned short* __restrict__ lwxT, unsigned short* __restrict__ lwhT,
    unsigned short* __restrict__ dwxT, unsigned short* __restrict__ dwhT,
    float* __restrict__ path_state, float* __restrict__ link_state)
{
    int b = blockIdx.x;
    int tid = threadIdx.x;
    if (b >= 1280) {
        const float* srcs[6] = {pgru_wx, pgru_wh, lgru_wx, lgru_wh, dgru_wx, dgru_wh};
        unsigned short* dsts[6] = {pwxT, pwhT, lwxT, lwhT, dwxT, dwhT};
        int i = (b - 1280) * 256 + tid;     // 0 .. 6*12288-1
        int mi = i / 12288, o = i - mi * 12288;
        int n = o >> 6, k = o & 63;
        dsts[mi][o] = f2bf(srcs[mi][k * 192 + n]);
        return;
    }
    __shared__ __align__(16) float w2s[4096];
    __shared__ float w1s[192], b1s[64], b2s[64];
    __shared__ float h1s[4][64];
    bool isPath = (b < 1024);
    const float* w1p = isPath ? pe_w1 : le_w1;
    const float* b1p = isPath ? pe_b1 : le_b1;
    const float* w2p = isPath ? pe_w2 : le_w2;
    const float* b2p = isPath ? pe_b2 : le_b2;
    for (int i = tid; i < 4096; i += 256) w2s[i] = w2p[i];
    if (tid < 192) w1s[tid] = w1p[tid];
    if (tid < 64) { b1s[tid] = b1p[tid]; b2s[tid] = b2p[tid]; }
    __syncthreads();
    int rl = tid >> 6, d = tid & 63;
    int base = (isPath ? b : (b - 1024)) * 16;
    for (int rp = 0; rp < 4; ++rp) {
        int row = base + rp * 4 + rl;
        float h;
        if (isPath) {
            float x0 = ft[row]  * 1e-4f;
            float x1 = fpk[row] * 1e-3f;
            float x2 = fps[row] * 1e-3f;
            h = b1s[d] + x0 * w1s[d] + x1 * w1s[64 + d] + x2 * w1s[128 + d];
        } else {
            float v = 0.0f;
            if (d < 16) v = ft[ptl[(row * 16 + d) * 2]];
            v += __shfl_down(v, 8);
            v += __shfl_down(v, 4);
            v += __shfl_down(v, 2);
            v += __shfl_down(v, 1);
            float ssum = __shfl(v, 0);
            float cv = cap[row];
            float load = ssum * frcp(cv * 1e9f);
            float x2 = (ldt[row] == 0) ? 1.0f : 0.0f;
            h = b1s[d] + cv * 0.01f * w1s[d] + load * w1s[64 + d] + x2 * w1s[128 + d];
        }
        h1s[rl][d] = fmaxf(h, 0.0f);
        __syncthreads();
        float acc = b2s[d];
#pragma unroll 8
        for (int k = 0; k < 64; ++k) acc += h1s[rl][k] * w2s[k * 64 + d];
        float* dst = isPath ? path_state : link_state;
        dst[(size_t)row * 64 + d] = fmaxf(acc, 0.0f);
        __syncthreads();
    }
}

// ---------------------------------------------------------------------------
// K3: device encoder, w2 staged in LDS
// ---------------------------------------------------------------------------
__global__ __launch_bounds__(256) void k_device_encode(
    const float* __restrict__ link_state, const int* __restrict__ ltn,
    const int* __restrict__ nodes,
    const float* __restrict__ w1, const float* __restrict__ b1,
    const float* __restrict__ w2, const float* __restrict__ b2,
    float* __restrict__ device_state)
{
    __shared__ __align__(16) float w2s[4096];
    __shared__ float h1s[4][64];
    int tid = threadIdx.x;
    for (int i = tid; i < 4096; i += 256) w2s[i] = w2[i];
    int rl = tid >> 6, d = tid & 63;
    int row = blockIdx.x * 4 + rl;
    float s = 0.0f;
#pragma unroll
    for (int m = 0; m < MG; ++m)
        s += link_state[(size_t)ltn[row * MG + m] * 64 + d];
#pragma unroll
    for (int o = 32; o > 0; o >>= 1) s += __shfl_xor(s, o);
    float dlm = s * (1.0f / 64.0f);
    float enc = (nodes[row] == 0) ? 1.0f : 0.0f;
    float h = b1[d] + enc * w1[d] + dlm * w1[64 + d];
    h1s[rl][d] = fmaxf(h, 0.0f);
    __syncthreads();
    float acc = b2[d];
#pragma unroll 8
    for (int k = 0; k < 64; ++k) acc += h1s[rl][k] * w2s[k * 64 + d];
    device_state[(size_t)row * 64 + d] = fmaxf(acc, 0.0f);
}

// ---------------------------------------------------------------------------
// K4: fused x-gather + xproj + 8-step GRU scan (+ fused readout when LAST).
// 16 paths/block (1024 blocks = 4/CU). h-state in registers, dbuf bf16 Hb,
// one barrier/step. Step-t h recycled into Xs[t] (LAST) or stored to pssb
// cooperatively (coalesced ushort4).
// ---------------------------------------------------------------------------
template <bool LAST>
__global__ __launch_bounds__(256, 4) void k_pscan(
    const float* __restrict__ ls, const float* __restrict__ dst,
    const int* __restrict__ ltp, const int* __restrict__ ntp,
    const unsigned short* __restrict__ wxT,   // bf16 [192][64]
    const unsigned short* __restrict__ whT,   // bf16 [192][64]
    const float* __restrict__ bx, const float* __restrict__ bh,
    float* __restrict__ path_state, unsigned short* __restrict__ pssb,
    const float* __restrict__ rw1, const float* __restrict__ rb1,
    const float* __restrict__ rw2, const float* __restrict__ rb2,
    const float* __restrict__ rw3, const float* __restrict__ rb3,
    const float* __restrict__ cap, float* __restrict__ out)
{
    __shared__ __align__(16) unsigned short Xs[8][16][72];  // bf16 x / h-store
    __shared__ __align__(16) unsigned short Hb[2][16][72];  // bf16 h dbuf
    __shared__ __align__(16) float rw1s[2048];
    __shared__ __align__(16) float rw2s[512];
    __shared__ float rw3s[16], rb1s[32], rb2s[16];
    int tid = threadIdx.x;
    int p0 = blockIdx.x * 16;

    if (LAST) {
        for (int i = tid; i < 2048; i += 256) rw1s[i] = rw1[i];
        for (int i = tid; i < 512; i += 256) rw2s[i] = rw2[i];
        if (tid < 16) rw3s[tid] = rw3[tid];
        if (tid < 32) rb1s[tid] = rb1[tid];
        if (tid < 16) rb2s[tid] = rb2[tid];
    }
    // stage h0 bf16
    {
        int r = tid >> 4, c0 = (tid & 15) * 4;
        float4 a = *(const float4*)(path_state + (size_t)(p0 + r) * 64 + c0);
        ushort4 u;
        u.x = f2bf(a.x); u.y = f2bf(a.y); u.z = f2bf(a.z); u.w = f2bf(a.w);
        *(ushort4*)&Hb[0][r][c0] = u;
    }
    // gather x = ls[ltp] + dst[ntp] -> bf16 Xs[t][m][k]; 2 threads per (m,t)
    {
        int t = tid >> 5, m = (tid >> 1) & 15, half = tid & 1;
        int gi = (p0 + m) * TT + t;
        int il = ltp[gi], in = ntp[gi];
        const float4* l4 = (const float4*)(ls + (size_t)il * 64 + half * 32);
        const float4* n4 = (const float4*)(dst + (size_t)in * 64 + half * 32);
#pragma unroll
        for (int j = 0; j < 8; ++j) {
            float4 a = l4[j], b = n4[j];
            ushort4 u;
            u.x = f2bf(a.x + b.x); u.y = f2bf(a.y + b.y);
            u.z = f2bf(a.z + b.z); u.w = f2bf(a.w + b.w);
            *(ushort4*)&Xs[t][m][half * 32 + j * 4] = u;
        }
    }

    int lane = tid & 63, w = tid >> 6;
    int c = lane & 15, q = lane >> 4;
    int d = 16 * w + c;
    short8b fx[3][2], fh[3][2];
#pragma unroll
    for (int g = 0; g < 3; ++g)
#pragma unroll
        for (int kt = 0; kt < 2; ++kt) {
            int off = (g * 64 + 16 * w + c) * 64 + kt * 32 + q * 8;
            fx[g][kt] = *(const short8b*)(wxT + off);
            fh[g][kt] = *(const short8b*)(whT + off);
        }
    float bz = bx[d] + bh[d];
    float br = bx[64 + d] + bh[64 + d];
    float bxc = bx[128 + d];
    float bhc = bh[128 + d];
    float hold[4];
#pragma unroll
    for (int r_ = 0; r_ < 4; ++r_)
        hold[r_] = path_state[(size_t)(p0 + q * 4 + r_) * 64 + d];
    __syncthreads();

    for (int t = 0; t < TT; ++t) {
        int rb = t & 1, wb = rb ^ 1;
        f32x4 ax[3], ah[3];
#pragma unroll
        for (int g = 0; g < 3; ++g) {
            ax[g] = (f32x4){0.f, 0.f, 0.f, 0.f};
            ah[g] = (f32x4){0.f, 0.f, 0.f, 0.f};
        }
#pragma unroll
        for (int kt = 0; kt < 2; ++kt) {
            short8b aX = *(const short8b*)&Xs[t][c][kt * 32 + q * 8];
            short8b aH = *(const short8b*)&Hb[rb][c][kt * 32 + q * 8];
#pragma unroll
            for (int g = 0; g < 3; ++g) {
                ax[g] = __builtin_amdgcn_mfma_f32_16x16x32_bf16(aX, fx[g][kt], ax[g], 0, 0, 0);
                ah[g] = __builtin_amdgcn_mfma_f32_16x16x32_bf16(aH, fh[g][kt], ah[g], 0, 0, 0);
            }
        }
#pragma unroll
        for (int r_ = 0; r_ < 4; ++r_) {
            float z  = sigmoidf_(ax[0][r_] + ah[0][r_] + bz);
            float rr = sigmoidf_(ax[1][r_] + ah[1][r_] + br);
            float cc = tanhf_(ax[2][r_] + bxc + rr * (ah[2][r_] + bhc));
            float hn = z * hold[r_] + (1.0f - z) * cc;
            hold[r_] = hn;
            Hb[wb][q * 4 + r_][d] = f2bf(hn);
        }
        __syncthreads();
        // cooperative copy of h_t: to Xs[t] (LAST) or coalesced pssb store
        {
            int r = tid >> 4, c0 = (tid & 15) * 4;
            ushort4 v = *(const ushort4*)&Hb[wb][r][c0];
            if (LAST) {
                *(ushort4*)&Xs[t][r][c0] = v;
            } else {
                *(ushort4*)(pssb + ((size_t)(p0 + r) * TT + t) * 64 + c0) = v;
            }
        }
    }
    if (!LAST) {
#pragma unroll
        for (int r_ = 0; r_ < 4; ++r_)
            path_state[(size_t)(p0 + q * 4 + r_) * 64 + d] = hold[r_];
        return;
    }
    // ===== fused readout: Xs[t][m][:] = h bf16 for all 8 steps =====
    __syncthreads();
    {
        int r = tid >> 1, hh = tid & 1;      // row r = m*8 + t
        int m = r >> 3, t = r & 7;
        short8b rowv[8];
#pragma unroll
        for (int j = 0; j < 8; ++j)
            rowv[j] = *(const short8b*)&Xs[t][m][j * 8];
        float a1[16];
#pragma unroll
        for (int i = 0; i < 16; ++i) a1[i] = 0.f;
#pragma unroll 4
        for (int k = 0; k < 64; ++k) {
            float x = bf2f((unsigned short)rowv[k >> 3][k & 7]);
            const float* wr = &rw1s[k * 32 + hh * 16];
            float4 wa = *(const float4*)(wr);
            float4 wb = *(const float4*)(wr + 4);
            float4 wc = *(const float4*)(wr + 8);
            float4 wd = *(const float4*)(wr + 12);
            a1[0]  += x * wa.x; a1[1]  += x * wa.y; a1[2]  += x * wa.z; a1[3]  += x * wa.w;
            a1[4]  += x * wb.x; a1[5]  += x * wb.y; a1[6]  += x * wb.z; a1[7]  += x * wb.w;
            a1[8]  += x * wc.x; a1[9]  += x * wc.y; a1[10] += x * wc.z; a1[11] += x * wc.w;
            a1[12] += x * wd.x; a1[13] += x * wd.y; a1[14] += x * wd.z; a1[15] += x * wd.w;
        }
#pragma unroll
        for (int i = 0; i < 16; ++i)
            a1[i] = fmaxf(a1[i] + rb1s[hh * 16 + i], 0.0f);
        // exchange halves with partner lane (tid^1)
        float h1[32];
#pragma unroll
        for (int i = 0; i < 16; ++i) {
            float o = __shfl_xor(a1[i], 1);
            h1[hh * 16 + i] = a1[i];
            h1[(1 - hh) * 16 + i] = o;
        }
        float a2[8];
#pragma unroll
        for (int i = 0; i < 8; ++i) a2[i] = 0.f;
#pragma unroll 4
        for (int k = 0; k < 32; ++k) {
            float x = h1[k];
            const float* wr = &rw2s[k * 16 + hh * 8];
            float4 wa = *(const float4*)(wr);
            float4 wb = *(const float4*)(wr + 4);
            a2[0] += x * wa.x; a2[1] += x * wa.y; a2[2] += x * wa.z; a2[3] += x * wa.w;
            a2[4] += x * wb.x; a2[5] += x * wb.y; a2[6] += x * wb.z; a2[7] += x * wb.w;
        }
#pragma unroll
        for (int i = 0; i < 8; ++i)
            a2[i] = fmaxf(a2[i] + rb2s[hh * 8 + i], 0.0f);
        float h2[16];
#pragma unroll
        for (int i = 0; i < 8; ++i) {
            float o = __shfl_xor(a2[i], 1);
            h2[hh * 8 + i] = a2[i];
            h2[(1 - hh) * 8 + i] = o;
        }
        float a3 = rb3[0];
#pragma unroll
        for (int k = 0; k < 16; ++k) a3 += h2[k] * rw3s[k];
        float occ = softplusf_(a3);
        float dcon = occ * frcp(cap[ltp[(p0 + m) * TT + t]]);
        float s = dcon;
        s += __shfl_xor(s, 2);
        s += __shfl_xor(s, 4);
        s += __shfl_xor(s, 8);
        if ((tid & 15) == 0) out[p0 + m] = s;
    }
}

// ---------------------------------------------------------------------------
// K6: merged link+device GRU update. Template Kg => fully unrolled gathers.
// ---------------------------------------------------------------------------
template <int Kg>
__device__ __forceinline__ void edge_body(
    const unsigned short* __restrict__ wxT, const unsigned short* __restrict__ whT,
    const float* __restrict__ bx, const float* __restrict__ bh,
    const int* __restrict__ p2e, const unsigned short* __restrict__ pssb,
    float* __restrict__ state, int blk)
{
    __shared__ int idxs[16 * Kg * 2];
    __shared__ __align__(16) unsigned short Ab[16][72];
    __shared__ __align__(16) unsigned short Hbs[16][72];
    __shared__ __align__(16) float Hf[16][68];
    int tid = threadIdx.x;
    int r0 = blk * 16;
    for (int i = tid; i < 16 * Kg * 2; i += 256)
        idxs[i] = p2e[(size_t)r0 * Kg * 2 + i];
    __syncthreads();
    {
        int r = tid >> 4, c4 = (tid & 15) * 4;
        int row = r0 + r;
        float4 s = {0.f, 0.f, 0.f, 0.f};
#pragma unroll
        for (int k = 0; k < Kg; ++k) {
            int pi = idxs[(r * Kg + k) * 2];
            int ti = idxs[(r * Kg + k) * 2 + 1];
            ushort4 v = *(const ushort4*)(pssb + ((size_t)pi * TT + ti - 1) * 64 + c4);
            s.x += bf2f(v.x); s.y += bf2f(v.y);
            s.z += bf2f(v.z); s.w += bf2f(v.w);
        }
        ushort4 ua;
        ua.x = f2bf(s.x); ua.y = f2bf(s.y); ua.z = f2bf(s.z); ua.w = f2bf(s.w);
        *(ushort4*)&Ab[r][c4] = ua;
        float4 hv = *(const float4*)(state + (size_t)row * 64 + c4);
        *(float4*)&Hf[r][c4] = hv;
        ushort4 uh;
        uh.x = f2bf(hv.x); uh.y = f2bf(hv.y); uh.z = f2bf(hv.z); uh.w = f2bf(hv.w);
        *(ushort4*)&Hbs[r][c4] = uh;
    }
    __syncthreads();
    int lane = tid & 63, w = tid >> 6;
    int c = lane & 15, q = lane >> 4;
    int d = 16 * w + c;
    short8b fx[3][2], fh[3][2];
#pragma unroll
    for (int g = 0; g < 3; ++g)
#pragma unroll
        for (int kt = 0; kt < 2; ++kt) {
            int off = (g * 64 + 16 * w + c) * 64 + kt * 32 + q * 8;
            fx[g][kt] = *(const short8b*)(wxT + off);
            fh[g][kt] = *(const short8b*)(whT + off);
        }
    f32x4 ax[3], ah[3];
#pragma unroll
    for (int g = 0; g < 3; ++g) {
        ax[g] = (f32x4){0.f, 0.f, 0.f, 0.f};
        ah[g] = (f32x4){0.f, 0.f, 0.f, 0.f};
    }
#pragma unroll
    for (int kt = 0; kt < 2; ++kt) {
        short8b aA = *(const short8b*)&Ab[c][kt * 32 + q * 8];
        short8b aH = *(const short8b*)&Hbs[c][kt * 32 + q * 8];
#pragma unroll
        for (int g = 0; g < 3; ++g) {
            ax[g] = __builtin_amdgcn_mfma_f32_16x16x32_bf16(aA, fx[g][kt], ax[g], 0, 0, 0);
            ah[g] = __builtin_amdgcn_mfma_f32_16x16x32_bf16(aH, fh[g][kt], ah[g], 0, 0, 0);
        }
    }
    float bz = bx[d] + bh[d];
    float br = bx[64 + d] + bh[64 + d];
    float bxc = bx[128 + d];
    float bhc = bh[128 + d];
#pragma unroll
    for (int r = 0; r < 4; ++r) {
        int m = q * 4 + r;
        float z  = sigmoidf_(ax[0][r] + ah[0][r] + bz);
        float rr = sigmoidf_(ax[1][r] + ah[1][r] + br);
        float cc = tanhf_(ax[2][r] + bxc + rr * (ah[2][r] + bhc));
        float hn = z * Hf[m][d] + (1.0f - z) * cc;
        state[(size_t)(r0 + m) * 64 + d] = hn;
    }
}

__global__ __launch_bounds__(256) void k_edge_merged(
    const unsigned short* __restrict__ lwxT, const unsigned short* __restrict__ lwhT,
    const float* __restrict__ lbx, const float* __restrict__ lbh,
    const int* __restrict__ ptl,
    const unsigned short* __restrict__ dwxT, const unsigned short* __restrict__ dwhT,
    const float* __restrict__ dbx, const float* __restrict__ dbh,
    const int* __restrict__ ptn,
    const unsigned short* __restrict__ pssb,
    float* __restrict__ link_state, float* __restrict__ device_state)
{
    int b = blockIdx.x;
    if (b < LN / 16) {
        edge_body<KG>(lwxT, lwhT, lbx, lbh, ptl, pssb, link_state, b);
    } else {
        edge_body<K2G>(dwxT, dwhT, dbx, dbh, ptn, pssb, device_state, b - LN / 16);
    }
}

// ---------------------------------------------------------------------------
extern "C" void kernel_launch(void* const* d_in, const int* in_sizes, int n_in,
                              void* d_out, int out_size, void* d_ws, size_t ws_size,
                              hipStream_t stream) {
    const float* ft   = (const float*)d_in[0];
    const float* fpk  = (const float*)d_in[1];
    const float* fps  = (const float*)d_in[2];
    const float* cap  = (const float*)d_in[3];
    const float* pe_w1 = (const float*)d_in[4];
    const float* pe_b1 = (const float*)d_in[5];
    const float* pe_w2 = (const float*)d_in[6];
    const float* pe_b2 = (const float*)d_in[7];
    const float* le_w1 = (const float*)d_in[8];
    const float* le_b1 = (const float*)d_in[9];
    const float* le_w2 = (const float*)d_in[10];
    const float* le_b2 = (const float*)d_in[11];
    const float* de_w1 = (const float*)d_in[12];
    const float* de_b1 = (const float*)d_in[13];
    const float* de_w2 = (const float*)d_in[14];
    const float* de_b2 = (const float*)d_in[15];
    const float* pgru_wx = (const float*)d_in[16];
    const float* pgru_wh = (const float*)d_in[17];
    const float* pgru_bx = (const float*)d_in[18];
    const float* pgru_bh = (const float*)d_in[19];
    const float* lgru_wx = (const float*)d_in[20];
    const float* lgru_wh = (const float*)d_in[21];
    const float* lgru_bx = (const float*)d_in[22];
    const float* lgru_bh = (const float*)d_in[23];
    const float* dgru_wx = (const float*)d_in[24];
    const float* dgru_wh = (const float*)d_in[25];
    const float* dgru_bx = (const float*)d_in[26];
    const float* dgru_bh = (const float*)d_in[27];
    const float* ro_w1 = (const float*)d_in[28];
    const float* ro_b1 = (const float*)d_in[29];
    const float* ro_w2 = (const float*)d_in[30];
    const float* ro_b2 = (const float*)d_in[31];
    const float* ro_w3 = (const float*)d_in[32];
    const float* ro_b3 = (const float*)d_in[33];
    const int* ltp   = (const int*)d_in[34];
    const int* ntp   = (const int*)d_in[35];
    const int* ptl   = (const int*)d_in[36];
    const int* ptn   = (const int*)d_in[37];
    const int* ltn   = (const int*)d_in[38];
    const int* nodes = (const int*)d_in[39];
    const int* ldt   = (const int*)d_in[40];
    float* out = (float*)d_out;

    char* ws = (char*)d_ws;
    float* path_state = (float*)ws;      ws += (size_t)PN * 64 * 4;
    float* link_state = (float*)ws;      ws += (size_t)LN * 64 * 4;
    float* device_state = (float*)ws;    ws += (size_t)NN * 64 * 4;
    unsigned short* pssb = (unsigned short*)ws; ws += (size_t)PN * TT * 64 * 2;
    unsigned short* pwxT = (unsigned short*)ws; ws += 192 * 64 * 2;
    unsigned short* pwhT = (unsigned short*)ws; ws += 192 * 64 * 2;
    unsigned short* lwxT = (unsigned short*)ws; ws += 192 * 64 * 2;
    unsigned short* lwhT = (unsigned short*)ws; ws += 192 * 64 * 2;
    unsigned short* dwxT = (unsigned short*)ws; ws += 192 * 64 * 2;
    unsigned short* dwhT = (unsigned short*)ws; ws += 192 * 64 * 2;

    k_setup<<<1568, 256, 0, stream>>>(ft, fpk, fps, cap, ptl, ldt,
                                      pe_w1, pe_b1, pe_w2, pe_b2,
                                      le_w1, le_b1, le_w2, le_b2,
                                      pgru_wx, pgru_wh, lgru_wx, lgru_wh,
                                      dgru_wx, dgru_wh,
                                      pwxT, pwhT, lwxT, lwhT, dwxT, dwhT,
                                      path_state, link_state);
    k_device_encode<<<NN / 4, 256, 0, stream>>>(link_state, ltn, nodes, de_w1,
                                                de_b1, de_w2, de_b2, device_state);
    for (int it = 0; it < ITER - 1; ++it) {
        k_pscan<false><<<PN / 16, 256, 0, stream>>>(
            link_state, device_state, ltp, ntp, pwxT, pwhT, pgru_bx, pgru_bh,
            path_state, pssb, ro_w1, ro_b1, ro_w2, ro_b2, ro_w3, ro_b3, cap, out);
        k_edge_merged<<<LN / 16 + NN / 16, 256, 0, stream>>>(
            lwxT, lwhT, lgru_bx, lgru_bh, ptl,
            dwxT, dwhT, dgru_bx, dgru_bh, ptn,
            pssb, link_state, device_state);
    }
    // final iteration: pscan + fused readout (edge update after it is dead work)
    k_pscan<true><<<PN / 16, 256, 0, stream>>>(
        link_state, device_state, ltp, ntp, pwxT, pwhT, pgru_bx, pgru_bh,
        path_state, pssb, ro_w1, ro_b1, ro_w2, ro_b2, ro_w3, ro_b3, cap, out);
}